// Round 1
// baseline (147.041 us; speedup 1.0000x reference)
//
#include <hip/hip_runtime.h>

#define EPSF 1e-7f

// B=8, IM(om)=32, K=256 (Hn*Wn=16*16), routing-IM=32, OD=16, IND=8, YK*XK=4.
// Grid: 512 blocks = (b*32+om) x 2 k-slices. Block: 512 threads.
// Thread t = (im<<4)|od owns W[b,om,:,:,im,od,:] (32 floats in VGPRs).
// Per 8-k chunk: all threads predict 8 tiles into LDS; then wave w routes tile k0+w.
__global__ __launch_bounds__(512, 4)
void caps_fused(const float* __restrict__ pc,   // [8,32,32,32,8]
                const float* __restrict__ Wt,   // [8,32,1,2,2,32,16,8]
                const float* __restrict__ bL,   // [1,32,16,16,32]
                float* __restrict__ out)        // [8,32,16,16,16]
{
    const int bid = blockIdx.x;
    const int bm  = bid >> 1;          // b*32 + om
    const int ks  = bid & 1;           // k-slice
    const int om  = bm & 31;

    const int t    = threadIdx.x;
    const int imw  = t >> 4;           // routing-im of this thread's W fragment
    const int od   = t & 15;
    const int wav  = t >> 6;
    const int lane = t & 63;

    // ---- W fragment: w[yx*8+e] = W[bm, yx, imw, od, e] ----
    float w[32];
    {
        const float* wb = Wt + (size_t)bm * 16384 + (size_t)((imw << 4) + od) * 8;
        #pragma unroll
        for (int yx = 0; yx < 4; ++yx) {
            const float4* p = (const float4*)(wb + yx * 4096);
            float4 a = p[0], b4 = p[1];
            w[yx*8+0]=a.x;  w[yx*8+1]=a.y;  w[yx*8+2]=a.z;  w[yx*8+3]=a.w;
            w[yx*8+4]=b4.x; w[yx*8+5]=b4.y; w[yx*8+6]=b4.z; w[yx*8+7]=b4.w;
        }
    }

    const float* pcb = pc  + (size_t)bm * 8192;   // [k][yx][e] = [256][4][8]
    const float* bLb = bL  + (size_t)om * 8192;   // [k][ir]    = [256][32]
    float*       ob  = out + (size_t)bm * 4096;   // [k][od]    = [256][16]

    __shared__ float s_x[8][512];                 // 8 tiles of x[im][od]

    const int k_lo = ks << 7;

    for (int k0 = k_lo; k0 < k_lo + 128; k0 += 8) {
        // ---------- phase 1: predict 8 tiles ----------
        #pragma unroll
        for (int kk = 0; kk < 8; ++kk) {
            const float* xi = pcb + (size_t)(k0 + kk) * 32;  // block-uniform addr
            float acc = 0.f;
            #pragma unroll
            for (int j = 0; j < 32; ++j) acc = fmaf(w[j], xi[j], acc);
            s_x[kk][t] = acc;
        }
        __syncthreads();

        // ---------- phase 2: wave `wav` routes tile k = k0+wav ----------
        const int k  = k0 + wav;
        const int h  = lane >> 5;      // od half: od in [8h, 8h+8)
        const int ir = lane & 31;      // routing im

        float xv[8];
        {
            const float4* xp = (const float4*)&s_x[wav][(ir << 4) + (h << 3)];
            float4 xa = xp[0], xb = xp[1];
            xv[0]=xa.x; xv[1]=xa.y; xv[2]=xa.z; xv[3]=xa.w;
            xv[4]=xb.x; xv[5]=xb.y; xv[6]=xb.z; xv[7]=xb.w;
        }

        float bb = bLb[(k << 5) + ir];
        float v[8];

        #pragma unroll
        for (int r = 0; r < 3; ++r) {
            // softmax over im (32 lanes per half; both halves hold all 32 im)
            float e = __expf(bb);
            float S = e;
            #pragma unroll
            for (int m = 1; m <= 16; m <<= 1) S += __shfl_xor(S, m, 64);
            float c = e / S;

            // v[od] = sum_im c*x[im][od]  (butterfly over the 32-lane half)
            #pragma unroll
            for (int j = 0; j < 8; ++j) v[j] = c * xv[j];
            #pragma unroll
            for (int m = 1; m <= 16; m <<= 1) {
                #pragma unroll
                for (int j = 0; j < 8; ++j) v[j] += __shfl_xor(v[j], m, 64);
            }

            // squash over all 16 od (own 8 + other half via xor-32)
            float sq = 0.f;
            #pragma unroll
            for (int j = 0; j < 8; ++j) sq = fmaf(v[j], v[j], sq);
            sq += __shfl_xor(sq, 32, 64);
            float scale = sq / ((1.f + sq) * sqrtf(sq + EPSF));
            #pragma unroll
            for (int j = 0; j < 8; ++j) v[j] *= scale;

            if (r < 2) {
                // bb[im] += sum_od x[im][od]*v[od]
                float d = 0.f;
                #pragma unroll
                for (int j = 0; j < 8; ++j) d = fmaf(xv[j], v[j], d);
                d += __shfl_xor(d, 32, 64);
                bb += d;
            }
        }

        // store final v (16 floats per tile), lanes with ir==0 (one per half)
        if (ir == 0) {
            float4* op = (float4*)(ob + (k << 4) + (h << 3));
            op[0] = make_float4(v[0], v[1], v[2], v[3]);
            op[1] = make_float4(v[4], v[5], v[6], v[7]);
        }
        __syncthreads();
    }
}

extern "C" void kernel_launch(void* const* d_in, const int* in_sizes, int n_in,
                              void* d_out, int out_size, void* d_ws, size_t ws_size,
                              hipStream_t stream)
{
    const float* pc = (const float*)d_in[0];
    const float* Wt = (const float*)d_in[1];
    const float* bL = (const float*)d_in[2];
    float*       o  = (float*)d_out;
    caps_fused<<<dim3(512), dim3(512), 0, stream>>>(pc, Wt, bL, o);
}

// Round 2
// 87.734 us; speedup vs baseline: 1.6760x; 1.6760x over previous
//
#include <hip/hip_runtime.h>

#define EPSF 1e-7f

// DPP-based add of partner lane's value. CTRL: 0xB1=xor1 (quad_perm[1,0,3,2]),
// 0x4E=xor2 (quad_perm[2,3,0,1]), 0x141=row_half_mirror (xor7), 0x140=row_mirror (xor15).
template<int CTRL>
__device__ __forceinline__ float dpp_add(float x) {
    int sh = __builtin_amdgcn_update_dpp(0, __float_as_int(x), CTRL, 0xF, 0xF, true);
    return x + __int_as_float(sh);
}

// all-reduce sum over the 16 lanes of a DPP row (lane bits 0..3).
// masks {1,2,7,15} are rank-4 over GF(2)^4 -> full butterfly allreduce.
__device__ __forceinline__ float row16_allsum(float x) {
    x = dpp_add<0xB1>(x);   // xor 1
    x = dpp_add<0x4E>(x);   // xor 2
    x = dpp_add<0x141>(x);  // xor 7
    x = dpp_add<0x140>(x);  // xor 15
    return x;
}

// all-reduce sum over lane bits 4,5 (the 4 g-groups).
__device__ __forceinline__ float gquad_allsum(float x) {
    x += __int_as_float(__builtin_amdgcn_ds_swizzle(__float_as_int(x), 0x401F)); // xor 16
    x += __shfl_xor(x, 32, 64);                                                  // xor 32
    return x;
}

// B=8, predict-m (=output OM')=32, K=256, routing-im=32, OD=16, IND=8, YK*XK=4.
// Grid: 1024 blocks = 256 (b*32+m) x 4 k-slices of 64. Block: 512 threads (8 waves).
// Phase 1: thread t=(im<<4)|od owns W[b,m,:,:,im,od,:] (32 f32 in VGPRs), predicts
//          8 tiles into LDS (x_in is block-uniform -> s_load SGPR operands).
// Phase 2: wave w routes tile k0+w. lane=(g<<4)|od, g owns im=8g..8g+7.
//          im-reductions: serial-8 + xor16/xor32. od-reductions: 4 DPP adds.
__global__ __launch_bounds__(512, 4)
void caps_fused(const float* __restrict__ pc,   // [8,32,32,32,8]
                const float* __restrict__ Wt,   // [8,32,1,2,2,32,16,8]
                const float* __restrict__ bL,   // [1,32,16,16,32]
                float* __restrict__ out)        // [8,32,16,16,16]
{
    const int bid = blockIdx.x;
    const int bm  = bid >> 2;          // b*32 + m
    const int ks  = bid & 3;           // k-slice of 64
    const int om  = bm & 31;

    const int t    = threadIdx.x;
    const int wav  = t >> 6;
    const int lane = t & 63;
    const int g    = lane >> 4;        // 0..3: owns im 8g..8g+7
    const int od   = lane & 15;
    const int imw  = t >> 4;           // phase-1 W ownership
    const int odw  = t & 15;

    // ---- W fragment: w[yx*8+e] = W[bm, yx, imw, odw, e] ----
    float w[32];
    {
        const float* wb = Wt + (size_t)bm * 16384 + (size_t)((imw << 4) + odw) * 8;
        #pragma unroll
        for (int yx = 0; yx < 4; ++yx) {
            const float4* p = (const float4*)(wb + yx * 4096);
            float4 a = p[0], b4 = p[1];
            w[yx*8+0]=a.x;  w[yx*8+1]=a.y;  w[yx*8+2]=a.z;  w[yx*8+3]=a.w;
            w[yx*8+4]=b4.x; w[yx*8+5]=b4.y; w[yx*8+6]=b4.z; w[yx*8+7]=b4.w;
        }
    }

    const float* pcb = pc  + (size_t)bm * 8192;   // [k][yx][e] = [256][4][8]
    const float* bLb = bL  + (size_t)om * 8192;   // [k][im]    = [256][32]
    float*       ob  = out + (size_t)bm * 4096;   // [k][od]    = [256][16]

    __shared__ float s_x[2][8][512];              // double-buffered: 8 tiles x[im][od]

    const int k_lo = ks << 6;

    #pragma unroll 2
    for (int c = 0; c < 8; ++c) {
        const int k0 = k_lo + (c << 3);
        const int p  = c & 1;

        // ---------- phase 1: predict 8 tiles into s_x[p] ----------
        #pragma unroll
        for (int kk = 0; kk < 8; ++kk) {
            const float* xi = pcb + (size_t)(k0 + kk) * 32;  // block-uniform -> s_load
            float acc = 0.f;
            #pragma unroll
            for (int j = 0; j < 32; ++j) acc = fmaf(w[j], xi[j], acc);
            s_x[p][kk][t] = acc;
        }

        // ---------- load routing logits for my tile (overlaps barrier) ----------
        const int k = k0 + wav;
        float bbv[8];                              // bb[8g..8g+7], replicated over od
        {
            const float4* bp = (const float4*)(bLb + (k << 5) + (g << 3));
            float4 b0 = bp[0], b1 = bp[1];
            bbv[0]=b0.x; bbv[1]=b0.y; bbv[2]=b0.z; bbv[3]=b0.w;
            bbv[4]=b1.x; bbv[5]=b1.y; bbv[6]=b1.z; bbv[7]=b1.w;
        }

        __syncthreads();

        // ---------- phase 2: wave `wav` routes tile k ----------
        float xu[8];                               // x[8g+j][od]
        #pragma unroll
        for (int j = 0; j < 8; ++j)
            xu[j] = s_x[p][wav][((g * 8 + j) << 4) + od];

        float vv = 0.f;
        #pragma unroll
        for (int r = 0; r < 3; ++r) {
            // softmax over im: e over own 8, serial sum, then g-allreduce
            float e[8], S = 0.f;
            #pragma unroll
            for (int j = 0; j < 8; ++j) { e[j] = __expf(bbv[j]); S += e[j]; }
            S = gquad_allsum(S);
            float inv = __builtin_amdgcn_rcpf(S);

            // v[od] = sum_im c*x[im][od]
            vv = 0.f;
            #pragma unroll
            for (int j = 0; j < 8; ++j) vv = fmaf(e[j] * inv, xu[j], vv);
            vv = gquad_allsum(vv);

            // squash over od (16-lane DPP row)
            float sq = row16_allsum(vv * vv);
            float scale = sq * __builtin_amdgcn_rcpf(1.f + sq) * rsqrtf(sq + EPSF);
            vv *= scale;

            // bb[im] += sum_od x[im][od]*v[od]
            if (r < 2) {
                #pragma unroll
                for (int j = 0; j < 8; ++j)
                    bbv[j] += row16_allsum(xu[j] * vv);
            }
        }

        if (g == 0) ob[(k << 4) + od] = vv;        // 16 consecutive floats per tile
    }
}

extern "C" void kernel_launch(void* const* d_in, const int* in_sizes, int n_in,
                              void* d_out, int out_size, void* d_ws, size_t ws_size,
                              hipStream_t stream)
{
    const float* pc = (const float*)d_in[0];
    const float* Wt = (const float*)d_in[1];
    const float* bL = (const float*)d_in[2];
    float*       o  = (float*)d_out;
    caps_fused<<<dim3(1024), dim3(512), 0, stream>>>(pc, Wt, bL, o);
}